// Round 2
// baseline (378.813 us; speedup 1.0000x reference)
//
#include <hip/hip_runtime.h>

#define NEG (-1e9f)
constexpr int NCLS   = 21;
constexpr int NBOX   = 8732;
constexpr int MAXOUT = 5;
constexpr int CAP    = NBOX;          // worst-case candidates per batch
constexpr float IOU_THR  = 0.5f;
constexpr float CONF_THR = 0.5f;

constexpr int TPB             = 128;
constexpr int BOXES_PER_BLOCK = TPB * 4;                                   // 512
constexpr int BPB             = (NBOX + BOXES_PER_BLOCK - 1) / BOXES_PER_BLOCK; // 18

// ---------------------------------------------------------------------------
// Fused kernel v2: decode + candidate compaction + last-block-done NMS,
// with ZERO bulk LDS (R1's 70KB static __shared__ was allocated by every
// block -> 2 blocks/CU -> 8% occupancy -> 270us. Only 4B of LDS remain).
// NMS phase instead re-reads candidate records from global (L2-hot, M is
// small for this input) and suppresses in place via owner-only global
// stores: lane i%64 is the unique reader AND writer of cand[i*2+1].x, so
// same-lane RAW ordering suffices - no fences inside the wave.
// Completion protocol (proven correct in R1, absmax 0.0): plain stores ->
// __threadfence release -> device-scope atomicAdd(done[b]) -> threadfence
// acquire -> last block runs one-wave NMS.
// Per-box arithmetic is IDENTICAL to the verified R5 kernel (bit-exact).
// Selection order: (score desc, original index asc) == jnp.argmax semantics.
// ---------------------------------------------------------------------------
__device__ __forceinline__ void process_box(
        const float* __restrict__ v,   // 25 floats for this box (registers)
        int b, int n,
        const float4* __restrict__ dbox4,
        float4* __restrict__ cand,
        int* __restrict__ cnt) {
    // decode (identical expression order to reference)
    float4 db = dbox4[n];
    float cy = (db.z + db.x) * 0.5f;
    float cx = (db.w + db.y) * 0.5f;
    float h  = db.z - db.x;
    float w  = db.w - db.y;
    float ncy = v[0] * h + cy;
    float ncx = v[1] * w + cx;
    float nh  = expf(v[2]) * h;
    float nw  = expf(v[3]) * w;
    float y1 = fminf(fmaxf(ncy - nh * 0.5f, 0.f), 1.f);
    float x1 = fminf(fmaxf(ncx - nw * 0.5f, 0.f), 1.f);
    float y2 = fminf(fmaxf(ncy + nh * 0.5f, 0.f), 1.f);
    float x2 = fminf(fmaxf(ncx + nw * 0.5f, 0.f), 1.f);

    // argmax(probs)==argmax(logits), first index on ties;
    // max prob = 1/sum(exp(x-max)), same accumulation order as reference
    float m = v[4];
    int am = 0;
#pragma unroll
    for (int j = 1; j < NCLS; j++) {
        float x = v[4 + j];
        if (x > m) { m = x; am = j; }
    }
    float sum = 0.f;
#pragma unroll
    for (int j = 0; j < NCLS; j++) sum += expf(v[4 + j] - m);
    float score = 1.0f / sum;

    if (am != 0 && score > CONF_THR) {
        int p = atomicAdd(&cnt[b], 1);
        if (p < CAP) {
            float4* c = cand + ((long long)b * CAP + p) * 2;
            c[0] = make_float4(y1, x1, y2, x2);
            c[1] = make_float4(score, (float)am, (float)n, 0.f);
        }
    }
}

__global__ __launch_bounds__(TPB) void fused_kernel(
        const float* __restrict__ logits,
        const float4* __restrict__ dbox4,
        float4* __restrict__ cand,
        int* __restrict__ cnt,
        int* __restrict__ done,
        float* __restrict__ out) {
    const int b   = blockIdx.x / BPB;
    const int blk = blockIdx.x % BPB;
    const int n0  = blk * BOXES_PER_BLOCK + threadIdx.x * 4;  // box idx within batch

    __shared__ int s_last;    // ONLY LDS in the kernel (4 bytes)

    // ---- decode phase -----------------------------------------------------
    if (n0 < NBOX) {
        // NBOX % 4 == 0 -> full aligned 4-box group guaranteed (no tail path)
        const float4* f4 =
            (const float4*)(logits + ((long long)b * NBOX + n0) * 25);
        float v[100];
#pragma unroll
        for (int k = 0; k < 25; k++) {
            float4 r = f4[k];
            v[4 * k + 0] = r.x; v[4 * k + 1] = r.y;
            v[4 * k + 2] = r.z; v[4 * k + 3] = r.w;
        }
#pragma unroll
        for (int j = 0; j < 4; j++)
            process_box(v + 25 * j, b, n0 + j, cand ? dbox4 : dbox4, cand, cnt);
    }

    // ---- completion protocol (proven in R1) -------------------------------
    __threadfence();                 // release: candidate stores visible device-wide
    __syncthreads();                 // all lanes' stores + fences done
    if (threadIdx.x == 0)
        s_last = (atomicAdd(&done[b], 1) == BPB - 1);
    __syncthreads();
    if (!s_last) return;             // not the last block for this batch
    if (threadIdx.x >= 64) return;   // NMS = exactly one wave
    __threadfence();                 // acquire: invalidate caches before reads

    // ---- NMS phase: zero-LDS, global-resident scores ----------------------
    const int lane = threadIdx.x;
    const int M = min(cnt[b], CAP);
    float4* cb = cand + (long long)b * CAP * 2;
    float* o = out + (long long)b * MAXOUT * 6;

    int k = 0;
    for (; k < MAXOUT; k++) {
        // selection scan: (score desc, original index asc)
        float bv = -INFINITY, boid = 3.0e38f;
        int bi = -1;
        for (int i = lane; i < M; i += 64) {
            float4 mrec = cb[i * 2 + 1];       // .x score (live), .z orig idx
            float v = mrec.x, oid = mrec.z;
            if (v > bv || (v == bv && oid < boid)) { bv = v; boid = oid; bi = i; }
        }
        for (int mm = 32; mm >= 1; mm >>= 1) {
            float v2 = __shfl_xor(bv,   mm, 64);
            float o2 = __shfl_xor(boid, mm, 64);
            int   i2 = __shfl_xor(bi,   mm, 64);
            if (v2 > bv || (v2 == bv && o2 < boid)) { bv = v2; boid = o2; bi = i2; }
        }
        if (bi < 0 || !(bv > CONF_THR)) break;   // this & later slots -> zeros

        float4 sb = cb[bi * 2];
        if (lane == 0) {
            float4 mm2 = cb[bi * 2 + 1];
            o[k * 6 + 0] = sb.x; o[k * 6 + 1] = sb.y;
            o[k * 6 + 2] = sb.z; o[k * 6 + 3] = sb.w;
            o[k * 6 + 4] = mm2.y; o[k * 6 + 5] = bv;
        }

        // suppression: owner-only in-place NEG store (suppresses bi too, IoU=1)
        float a1 = (sb.z - sb.x) * (sb.w - sb.y);
        for (int i = lane; i < M; i += 64) {
            float4 c = cb[i * 2];
            float tly = fmaxf(sb.x, c.x);
            float tlx = fmaxf(sb.y, c.y);
            float bry = fminf(sb.z, c.z);
            float brx = fminf(sb.w, c.w);
            float wh0 = fmaxf(bry - tly, 0.f);
            float wh1 = fmaxf(brx - tlx, 0.f);
            float inter = wh0 * wh1;
            float a2 = (c.z - c.x) * (c.w - c.y);
            float iou = inter / (a1 + a2 - inter + 1e-12f);
            if (iou > IOU_THR)
                ((float*)&cb[i * 2 + 1])[0] = NEG;   // owner lane i%64 only
        }
    }
    for (int j = k * 6 + lane; j < MAXOUT * 6; j += 64) o[j] = 0.f;
}

extern "C" void kernel_launch(void* const* d_in, const int* in_sizes, int n_in,
                              void* d_out, int out_size, void* d_ws, size_t ws_size,
                              hipStream_t stream) {
    const float* logits = (const float*)d_in[0];
    const float4* dbox4 = (const float4*)d_in[1];
    float* out          = (float*)d_out;

    const int N = in_sizes[1] / 4;            // 8732
    const int B = in_sizes[0] / (N * 25);     // 128

    // ws layout: [cnt: B ints][done: B ints][pad to 16B][cand: B*CAP*2 float4]
    int* cnt  = (int*)d_ws;
    int* done = cnt + B;
    float4* cand = (float4*)((char*)d_ws +
        ((2 * (size_t)B * sizeof(int) + 15) & ~(size_t)15));

    hipMemsetAsync(d_ws, 0, 2 * (size_t)B * sizeof(int), stream);
    fused_kernel<<<B * BPB, TPB, 0, stream>>>(logits, dbox4, cand, cnt, done, out);
}

// Round 3
// 187.451 us; speedup vs baseline: 2.0209x; 2.0209x over previous
//
#include <hip/hip_runtime.h>

#define NEG (-1e9f)
constexpr int NCLS   = 21;
constexpr int NBOX   = 8732;
constexpr int MAXOUT = 5;
constexpr int CAP    = NBOX;          // worst-case candidates per batch
constexpr float IOU_THR  = 0.5f;
constexpr float CONF_THR = 0.5f;

constexpr int TPB             = 128;
constexpr int BOXES_PER_BLOCK = TPB * 4;                                   // 512
constexpr int BPB             = (NBOX + BOXES_PER_BLOCK - 1) / BOXES_PER_BLOCK; // 18

using u64 = unsigned long long;

// ---------------------------------------------------------------------------
// Fused kernel v3: decode + compaction + last-block-done NMS, ZERO FENCES.
// R1/R2 post-mortem: per-block __threadfence (release) = buffer_wbl2 sc1,
// 4608 of them serialized at the coherence fabric ~= the whole 266us (R1@8%
// occ == R2@34% occ -> duration tracks fence count, not waves). Replacement:
// candidate words are relaxed AGENT-scope atomic stores (coherent at the
// device point when vmcnt retires; __syncthreads drains vmcnt before
// s_barrier), then a relaxed agent-scope atomicAdd(done[b]); readers use
// relaxed agent-scope atomic loads. Standard split-K flag pattern; no wbl2,
// no buffer_inv anywhere.
// NMS: M<=64 (always true for this input, M~40-60) -> fully register-
// resident: 1 candidate/lane, butterfly-shuffle selection (score desc, orig
// idx asc == jnp.argmax), in-register suppression. M>64 fallback keeps
// worst-case correctness via global atomic loads/stores.
// Per-box decode/softmax arithmetic IDENTICAL to the proven kernel
// (bit-exact, absmax 0.0 in R0-R2).
// Candidate record: u64 w0=(y1,x1) w1=(y2,x2) w2=(score,oid) w3=(cls,0).
// ---------------------------------------------------------------------------

__device__ __forceinline__ u64 pk2(float a, float b) {
    union { float f[2]; u64 u; } x; x.f[0] = a; x.f[1] = b; return x.u;
}
__device__ __forceinline__ float lo2(u64 u) { union { u64 v; float f[2]; } x; x.v = u; return x.f[0]; }
__device__ __forceinline__ float hi2(u64 u) { union { u64 v; float f[2]; } x; x.v = u; return x.f[1]; }

__device__ __forceinline__ void ast(u64* p, u64 v) {
    __hip_atomic_store(p, v, __ATOMIC_RELAXED, __HIP_MEMORY_SCOPE_AGENT);
}
__device__ __forceinline__ u64 ald(const u64* p) {
    return __hip_atomic_load(p, __ATOMIC_RELAXED, __HIP_MEMORY_SCOPE_AGENT);
}

__device__ __forceinline__ void process_box(
        const float* __restrict__ v,   // 25 floats for this box (registers)
        int b, int n,
        const float4* __restrict__ dbox4,
        u64* __restrict__ cand,
        int* __restrict__ cnt) {
    // decode (identical expression order to reference)
    float4 db = dbox4[n];
    float cy = (db.z + db.x) * 0.5f;
    float cx = (db.w + db.y) * 0.5f;
    float h  = db.z - db.x;
    float w  = db.w - db.y;
    float ncy = v[0] * h + cy;
    float ncx = v[1] * w + cx;
    float nh  = expf(v[2]) * h;
    float nw  = expf(v[3]) * w;
    float y1 = fminf(fmaxf(ncy - nh * 0.5f, 0.f), 1.f);
    float x1 = fminf(fmaxf(ncx - nw * 0.5f, 0.f), 1.f);
    float y2 = fminf(fmaxf(ncy + nh * 0.5f, 0.f), 1.f);
    float x2 = fminf(fmaxf(ncx + nw * 0.5f, 0.f), 1.f);

    // argmax(probs)==argmax(logits), first index on ties;
    // max prob = 1/sum(exp(x-max)), same accumulation order as reference
    float m = v[4];
    int am = 0;
#pragma unroll
    for (int j = 1; j < NCLS; j++) {
        float x = v[4 + j];
        if (x > m) { m = x; am = j; }
    }
    float sum = 0.f;
#pragma unroll
    for (int j = 0; j < NCLS; j++) sum += expf(v[4 + j] - m);
    float score = 1.0f / sum;

    if (am != 0 && score > CONF_THR) {
        int p = atomicAdd(&cnt[b], 1);   // device-scope RMW (coherent point)
        if (p < CAP) {
            u64* c = cand + ((long long)b * CAP + p) * 4;
            ast(c + 0, pk2(y1, x1));
            ast(c + 1, pk2(y2, x2));
            ast(c + 2, pk2(score, (float)n));
            ast(c + 3, pk2((float)am, 0.f));
        }
    }
}

__global__ __launch_bounds__(TPB) void fused_kernel(
        const float* __restrict__ logits,
        const float4* __restrict__ dbox4,
        u64* __restrict__ cand,
        int* __restrict__ cnt,
        int* __restrict__ done,
        float* __restrict__ out) {
    const int b   = blockIdx.x / BPB;
    const int blk = blockIdx.x % BPB;
    const int n0  = blk * BOXES_PER_BLOCK + threadIdx.x * 4;  // box idx within batch

    __shared__ int s_last;    // ONLY LDS in the kernel (4 bytes)

    // ---- decode phase -----------------------------------------------------
    if (n0 < NBOX) {
        // NBOX % 4 == 0 -> full aligned 4-box group guaranteed (no tail path)
        const float4* f4 =
            (const float4*)(logits + ((long long)b * NBOX + n0) * 25);
        float v[100];
#pragma unroll
        for (int k = 0; k < 25; k++) {
            float4 r = f4[k];
            v[4 * k + 0] = r.x; v[4 * k + 1] = r.y;
            v[4 * k + 2] = r.z; v[4 * k + 3] = r.w;
        }
#pragma unroll
        for (int j = 0; j < 4; j++)
            process_box(v + 25 * j, b, n0 + j, dbox4, cand, cnt);
    }

    // ---- completion protocol: zero fences ---------------------------------
    // __syncthreads drains each wave's vmcnt (sc-flagged stores then globally
    // visible) before the relaxed device-scope RMW on done[b].
    __syncthreads();
    if (threadIdx.x == 0)
        s_last = (__hip_atomic_fetch_add(&done[b], 1, __ATOMIC_RELAXED,
                                         __HIP_MEMORY_SCOPE_AGENT) == BPB - 1);
    __syncthreads();
    if (!s_last) return;             // not the last block for this batch
    if (threadIdx.x >= 64) return;   // NMS = exactly one wave

    // ---- NMS phase --------------------------------------------------------
    const int lane = threadIdx.x;
    const int M = min((int)__hip_atomic_load(&cnt[b], __ATOMIC_RELAXED,
                                             __HIP_MEMORY_SCOPE_AGENT), CAP);
    const u64* cb = cand + (long long)b * CAP * 4;
    float* o = out + (long long)b * MAXOUT * 6;

    int k = 0;
    if (M <= 64) {
        // register-resident fast path: one candidate per lane, zero memory
        // traffic inside the selection loop.
        float sc = -INFINITY, oid = 3.0e38f;
        float y1 = 0.f, x1 = 0.f, y2 = 0.f, x2 = 0.f, cls = 0.f;
        if (lane < M) {
            const u64* c = cb + (long long)lane * 4;
            u64 w0 = ald(c + 0), w1 = ald(c + 1), w2 = ald(c + 2), w3 = ald(c + 3);
            y1 = lo2(w0); x1 = hi2(w0);
            y2 = lo2(w1); x2 = hi2(w1);
            sc = lo2(w2); oid = hi2(w2);
            cls = lo2(w3);
        }
        for (; k < MAXOUT; k++) {
            float bv = sc, boid = oid;
            int bi = (lane < M) ? lane : -1;
            for (int mm = 32; mm >= 1; mm >>= 1) {
                float v2 = __shfl_xor(bv,   mm, 64);
                float o2 = __shfl_xor(boid, mm, 64);
                int   i2 = __shfl_xor(bi,   mm, 64);
                if (v2 > bv || (v2 == bv && o2 < boid)) { bv = v2; boid = o2; bi = i2; }
            }
            if (bi < 0 || !(bv > CONF_THR)) break;   // this & later slots -> zeros

            float sy1 = __shfl(y1, bi, 64), sx1 = __shfl(x1, bi, 64);
            float sy2 = __shfl(y2, bi, 64), sx2 = __shfl(x2, bi, 64);
            float scl = __shfl(cls, bi, 64);
            if (lane == 0) {
                o[k * 6 + 0] = sy1; o[k * 6 + 1] = sx1;
                o[k * 6 + 2] = sy2; o[k * 6 + 3] = sx2;
                o[k * 6 + 4] = scl; o[k * 6 + 5] = bv;
            }
            // in-register suppression (selected lane suppresses itself, IoU=1)
            float a1 = (sy2 - sy1) * (sx2 - sx1);
            float tly = fmaxf(sy1, y1);
            float tlx = fmaxf(sx1, x1);
            float bry = fminf(sy2, y2);
            float brx = fminf(sx2, x2);
            float wh0 = fmaxf(bry - tly, 0.f);
            float wh1 = fmaxf(brx - tlx, 0.f);
            float inter = wh0 * wh1;
            float a2 = (y2 - y1) * (x2 - x1);
            float iou = inter / (a1 + a2 - inter + 1e-12f);
            if (lane < M && iou > IOU_THR) sc = NEG;
        }
    } else {
        // general path (never taken for this input; worst-case correctness)
        for (; k < MAXOUT; k++) {
            float bv = -INFINITY, boid = 3.0e38f;
            int bi = -1;
            for (int i = lane; i < M; i += 64) {
                u64 w2 = ald(cb + (long long)i * 4 + 2);
                float v = lo2(w2), od = hi2(w2);
                if (v > bv || (v == bv && od < boid)) { bv = v; boid = od; bi = i; }
            }
            for (int mm = 32; mm >= 1; mm >>= 1) {
                float v2 = __shfl_xor(bv,   mm, 64);
                float o2 = __shfl_xor(boid, mm, 64);
                int   i2 = __shfl_xor(bi,   mm, 64);
                if (v2 > bv || (v2 == bv && o2 < boid)) { bv = v2; boid = o2; bi = i2; }
            }
            if (bi < 0 || !(bv > CONF_THR)) break;

            u64 sw0 = ald(cb + (long long)bi * 4 + 0);
            u64 sw1 = ald(cb + (long long)bi * 4 + 1);
            float sy1 = lo2(sw0), sx1 = hi2(sw0), sy2 = lo2(sw1), sx2 = hi2(sw1);
            if (lane == 0) {
                u64 sw3 = ald(cb + (long long)bi * 4 + 3);
                o[k * 6 + 0] = sy1; o[k * 6 + 1] = sx1;
                o[k * 6 + 2] = sy2; o[k * 6 + 3] = sx2;
                o[k * 6 + 4] = lo2(sw3); o[k * 6 + 5] = bv;
            }
            float a1 = (sy2 - sy1) * (sx2 - sx1);
            for (int i = lane; i < M; i += 64) {
                u64 w0 = ald(cb + (long long)i * 4 + 0);
                u64 w1 = ald(cb + (long long)i * 4 + 1);
                float cy1 = lo2(w0), cx1 = hi2(w0), cy2 = lo2(w1), cx2 = hi2(w1);
                float tly = fmaxf(sy1, cy1);
                float tlx = fmaxf(sx1, cx1);
                float bry = fminf(sy2, cy2);
                float brx = fminf(sx2, cx2);
                float wh0 = fmaxf(bry - tly, 0.f);
                float wh1 = fmaxf(brx - tlx, 0.f);
                float inter = wh0 * wh1;
                float a2 = (cy2 - cy1) * (cx2 - cx1);
                float iou = inter / (a1 + a2 - inter + 1e-12f);
                if (iou > IOU_THR) {
                    u64 w2 = ald(cb + (long long)i * 4 + 2);   // owner lane only
                    ast((u64*)(cb + (long long)i * 4 + 2), pk2(NEG, hi2(w2)));
                }
            }
        }
    }
    for (int j = k * 6 + lane; j < MAXOUT * 6; j += 64) o[j] = 0.f;
}

extern "C" void kernel_launch(void* const* d_in, const int* in_sizes, int n_in,
                              void* d_out, int out_size, void* d_ws, size_t ws_size,
                              hipStream_t stream) {
    const float* logits = (const float*)d_in[0];
    const float4* dbox4 = (const float4*)d_in[1];
    float* out          = (float*)d_out;

    const int N = in_sizes[1] / 4;            // 8732
    const int B = in_sizes[0] / (N * 25);     // 128

    // ws layout: [cnt: B ints][done: B ints][pad to 16B][cand: B*CAP*4 u64]
    int* cnt  = (int*)d_ws;
    int* done = cnt + B;
    u64* cand = (u64*)((char*)d_ws +
        ((2 * (size_t)B * sizeof(int) + 15) & ~(size_t)15));

    hipMemsetAsync(d_ws, 0, 2 * (size_t)B * sizeof(int), stream);
    fused_kernel<<<B * BPB, TPB, 0, stream>>>(logits, dbox4, cand, cnt, done, out);
}

// Round 4
// 187.072 us; speedup vs baseline: 2.0250x; 1.0020x over previous
//
#include <hip/hip_runtime.h>

#define NEG (-1e9f)
constexpr int NCLS   = 21;
constexpr int NBOX   = 8732;
constexpr int MAXOUT = 5;
constexpr int CAP    = NBOX;          // worst-case candidates per batch
constexpr float IOU_THR  = 0.5f;
constexpr float CONF_THR = 0.5f;

constexpr int TPB             = 128;
constexpr int BOXES_PER_BLOCK = TPB * 4;                                   // 512
constexpr int BPB             = (NBOX + BOXES_PER_BLOCK - 1) / BOXES_PER_BLOCK; // 18

using u64 = unsigned long long;

// ---------------------------------------------------------------------------
// Fused kernel v4: decode + compaction + last-block-done NMS, zero fences
// (R3 protocol, proven absmax 0.0), now MLP-unlocked.
// R3 post-mortem: 70us @ 890 GB/s, VALU 16%, occ 29% -> latency*parallelism
// bound. VGPR_Count=48 showed the compiler pipelined the 25 float4 loads
// into ~4-7-deep groups -> ~5 outstanding loads/wave -> Little's law gives
// exactly the observed ~0.9 TB/s. Fix: __launch_bounds__(128,3) raises the
// register budget (~<=168 VGPR, still 12 waves/CU) and an explicit float4
// r[25] tile + sched_barrier(0) pins ALL 25 loads issued before any use:
// 25 in-flight 16B loads/wave * ~12-16 waves/CU -> ~5-6 KB/CU in flight
// -> ~4-6 TB/s logical, decode floor ~20-26us.
// NMS: M<=64 register-resident fast path (this input: M~40-60), M>64
// global fallback for worst-case correctness. Relaxed agent-scope atomics
// for cand/done (coherent at vmcnt retire; __syncthreads drains vmcnt).
// Per-box decode/softmax arithmetic IDENTICAL to the proven kernel
// (bit-exact, absmax 0.0 in R0-R3).
// Candidate record: u64 w0=(y1,x1) w1=(y2,x2) w2=(score,oid) w3=(cls,0).
// ---------------------------------------------------------------------------

__device__ __forceinline__ u64 pk2(float a, float b) {
    union { float f[2]; u64 u; } x; x.f[0] = a; x.f[1] = b; return x.u;
}
__device__ __forceinline__ float lo2(u64 u) { union { u64 v; float f[2]; } x; x.v = u; return x.f[0]; }
__device__ __forceinline__ float hi2(u64 u) { union { u64 v; float f[2]; } x; x.v = u; return x.f[1]; }

__device__ __forceinline__ void ast(u64* p, u64 v) {
    __hip_atomic_store(p, v, __ATOMIC_RELAXED, __HIP_MEMORY_SCOPE_AGENT);
}
__device__ __forceinline__ u64 ald(const u64* p) {
    return __hip_atomic_load(p, __ATOMIC_RELAXED, __HIP_MEMORY_SCOPE_AGENT);
}

__device__ __forceinline__ void process_box(
        const float* __restrict__ v,   // 25 floats for this box (registers)
        int b, int n,
        const float4* __restrict__ dbox4,
        u64* __restrict__ cand,
        int* __restrict__ cnt) {
    // decode (identical expression order to reference)
    float4 db = dbox4[n];
    float cy = (db.z + db.x) * 0.5f;
    float cx = (db.w + db.y) * 0.5f;
    float h  = db.z - db.x;
    float w  = db.w - db.y;
    float ncy = v[0] * h + cy;
    float ncx = v[1] * w + cx;
    float nh  = expf(v[2]) * h;
    float nw  = expf(v[3]) * w;
    float y1 = fminf(fmaxf(ncy - nh * 0.5f, 0.f), 1.f);
    float x1 = fminf(fmaxf(ncx - nw * 0.5f, 0.f), 1.f);
    float y2 = fminf(fmaxf(ncy + nh * 0.5f, 0.f), 1.f);
    float x2 = fminf(fmaxf(ncx + nw * 0.5f, 0.f), 1.f);

    // argmax(probs)==argmax(logits), first index on ties;
    // max prob = 1/sum(exp(x-max)), same accumulation order as reference
    float m = v[4];
    int am = 0;
#pragma unroll
    for (int j = 1; j < NCLS; j++) {
        float x = v[4 + j];
        if (x > m) { m = x; am = j; }
    }
    float sum = 0.f;
#pragma unroll
    for (int j = 0; j < NCLS; j++) sum += expf(v[4 + j] - m);
    float score = 1.0f / sum;

    if (am != 0 && score > CONF_THR) {
        int p = atomicAdd(&cnt[b], 1);   // device-scope RMW (coherent point)
        if (p < CAP) {
            u64* c = cand + ((long long)b * CAP + p) * 4;
            ast(c + 0, pk2(y1, x1));
            ast(c + 1, pk2(y2, x2));
            ast(c + 2, pk2(score, (float)n));
            ast(c + 3, pk2((float)am, 0.f));
        }
    }
}

__global__ __launch_bounds__(TPB, 3) void fused_kernel(
        const float* __restrict__ logits,
        const float4* __restrict__ dbox4,
        u64* __restrict__ cand,
        int* __restrict__ cnt,
        int* __restrict__ done,
        float* __restrict__ out) {
    const int b   = blockIdx.x / BPB;
    const int blk = blockIdx.x % BPB;
    const int n0  = blk * BOXES_PER_BLOCK + threadIdx.x * 4;  // box idx within batch

    __shared__ int s_last;    // ONLY LDS in the kernel (4 bytes)

    // ---- decode phase -----------------------------------------------------
    if (n0 < NBOX) {
        // NBOX % 4 == 0 -> full aligned 4-box group guaranteed (no tail path)
        const float4* f4 =
            (const float4*)(logits + ((long long)b * NBOX + n0) * 25);
        // issue ALL 25 independent 16B loads back-to-back (MLP = 25/wave),
        // then pin with sched_barrier so extraction can't hoist above / loads
        // can't sink below.
        float4 r[25];
#pragma unroll
        for (int k = 0; k < 25; k++) r[k] = f4[k];
        __builtin_amdgcn_sched_barrier(0);

        float v[100];
#pragma unroll
        for (int k = 0; k < 25; k++) {
            v[4 * k + 0] = r[k].x; v[4 * k + 1] = r[k].y;
            v[4 * k + 2] = r[k].z; v[4 * k + 3] = r[k].w;
        }
#pragma unroll
        for (int j = 0; j < 4; j++)
            process_box(v + 25 * j, b, n0 + j, dbox4, cand, cnt);
    }

    // ---- completion protocol: zero fences (proven R3) ---------------------
    // __syncthreads drains each wave's vmcnt (sc-flagged stores then globally
    // visible) before the relaxed device-scope RMW on done[b].
    __syncthreads();
    if (threadIdx.x == 0)
        s_last = (__hip_atomic_fetch_add(&done[b], 1, __ATOMIC_RELAXED,
                                         __HIP_MEMORY_SCOPE_AGENT) == BPB - 1);
    __syncthreads();
    if (!s_last) return;             // not the last block for this batch
    if (threadIdx.x >= 64) return;   // NMS = exactly one wave

    // ---- NMS phase (verbatim R3, proven) ----------------------------------
    const int lane = threadIdx.x;
    const int M = min((int)__hip_atomic_load(&cnt[b], __ATOMIC_RELAXED,
                                             __HIP_MEMORY_SCOPE_AGENT), CAP);
    const u64* cb = cand + (long long)b * CAP * 4;
    float* o = out + (long long)b * MAXOUT * 6;

    int k = 0;
    if (M <= 64) {
        // register-resident fast path: one candidate per lane, zero memory
        // traffic inside the selection loop.
        float sc = -INFINITY, oid = 3.0e38f;
        float y1 = 0.f, x1 = 0.f, y2 = 0.f, x2 = 0.f, cls = 0.f;
        if (lane < M) {
            const u64* c = cb + (long long)lane * 4;
            u64 w0 = ald(c + 0), w1 = ald(c + 1), w2 = ald(c + 2), w3 = ald(c + 3);
            y1 = lo2(w0); x1 = hi2(w0);
            y2 = lo2(w1); x2 = hi2(w1);
            sc = lo2(w2); oid = hi2(w2);
            cls = lo2(w3);
        }
        for (; k < MAXOUT; k++) {
            float bv = sc, boid = oid;
            int bi = (lane < M) ? lane : -1;
            for (int mm = 32; mm >= 1; mm >>= 1) {
                float v2 = __shfl_xor(bv,   mm, 64);
                float o2 = __shfl_xor(boid, mm, 64);
                int   i2 = __shfl_xor(bi,   mm, 64);
                if (v2 > bv || (v2 == bv && o2 < boid)) { bv = v2; boid = o2; bi = i2; }
            }
            if (bi < 0 || !(bv > CONF_THR)) break;   // this & later slots -> zeros

            float sy1 = __shfl(y1, bi, 64), sx1 = __shfl(x1, bi, 64);
            float sy2 = __shfl(y2, bi, 64), sx2 = __shfl(x2, bi, 64);
            float scl = __shfl(cls, bi, 64);
            if (lane == 0) {
                o[k * 6 + 0] = sy1; o[k * 6 + 1] = sx1;
                o[k * 6 + 2] = sy2; o[k * 6 + 3] = sx2;
                o[k * 6 + 4] = scl; o[k * 6 + 5] = bv;
            }
            // in-register suppression (selected lane suppresses itself, IoU=1)
            float a1 = (sy2 - sy1) * (sx2 - sx1);
            float tly = fmaxf(sy1, y1);
            float tlx = fmaxf(sx1, x1);
            float bry = fminf(sy2, y2);
            float brx = fminf(sx2, x2);
            float wh0 = fmaxf(bry - tly, 0.f);
            float wh1 = fmaxf(brx - tlx, 0.f);
            float inter = wh0 * wh1;
            float a2 = (y2 - y1) * (x2 - x1);
            float iou = inter / (a1 + a2 - inter + 1e-12f);
            if (lane < M && iou > IOU_THR) sc = NEG;
        }
    } else {
        // general path (never taken for this input; worst-case correctness)
        for (; k < MAXOUT; k++) {
            float bv = -INFINITY, boid = 3.0e38f;
            int bi = -1;
            for (int i = lane; i < M; i += 64) {
                u64 w2 = ald(cb + (long long)i * 4 + 2);
                float v = lo2(w2), od = hi2(w2);
                if (v > bv || (v == bv && od < boid)) { bv = v; boid = od; bi = i; }
            }
            for (int mm = 32; mm >= 1; mm >>= 1) {
                float v2 = __shfl_xor(bv,   mm, 64);
                float o2 = __shfl_xor(boid, mm, 64);
                int   i2 = __shfl_xor(bi,   mm, 64);
                if (v2 > bv || (v2 == bv && o2 < boid)) { bv = v2; boid = o2; bi = i2; }
            }
            if (bi < 0 || !(bv > CONF_THR)) break;

            u64 sw0 = ald(cb + (long long)bi * 4 + 0);
            u64 sw1 = ald(cb + (long long)bi * 4 + 1);
            float sy1 = lo2(sw0), sx1 = hi2(sw0), sy2 = lo2(sw1), sx2 = hi2(sw1);
            if (lane == 0) {
                u64 sw3 = ald(cb + (long long)bi * 4 + 3);
                o[k * 6 + 0] = sy1; o[k * 6 + 1] = sx1;
                o[k * 6 + 2] = sy2; o[k * 6 + 3] = sx2;
                o[k * 6 + 4] = lo2(sw3); o[k * 6 + 5] = bv;
            }
            float a1 = (sy2 - sy1) * (sx2 - sx1);
            for (int i = lane; i < M; i += 64) {
                u64 w0 = ald(cb + (long long)i * 4 + 0);
                u64 w1 = ald(cb + (long long)i * 4 + 1);
                float cy1 = lo2(w0), cx1 = hi2(w0), cy2 = lo2(w1), cx2 = hi2(w1);
                float tly = fmaxf(sy1, cy1);
                float tlx = fmaxf(sx1, cx1);
                float bry = fminf(sy2, cy2);
                float brx = fminf(sx2, cx2);
                float wh0 = fmaxf(bry - tly, 0.f);
                float wh1 = fmaxf(brx - tlx, 0.f);
                float inter = wh0 * wh1;
                float a2 = (cy2 - cy1) * (cx2 - cx1);
                float iou = inter / (a1 + a2 - inter + 1e-12f);
                if (iou > IOU_THR) {
                    u64 w2 = ald(cb + (long long)i * 4 + 2);   // owner lane only
                    ast((u64*)(cb + (long long)i * 4 + 2), pk2(NEG, hi2(w2)));
                }
            }
        }
    }
    for (int j = k * 6 + lane; j < MAXOUT * 6; j += 64) o[j] = 0.f;
}

extern "C" void kernel_launch(void* const* d_in, const int* in_sizes, int n_in,
                              void* d_out, int out_size, void* d_ws, size_t ws_size,
                              hipStream_t stream) {
    const float* logits = (const float*)d_in[0];
    const float4* dbox4 = (const float4*)d_in[1];
    float* out          = (float*)d_out;

    const int N = in_sizes[1] / 4;            // 8732
    const int B = in_sizes[0] / (N * 25);     // 128

    // ws layout: [cnt: B ints][done: B ints][pad to 16B][cand: B*CAP*4 u64]
    int* cnt  = (int*)d_ws;
    int* done = cnt + B;
    u64* cand = (u64*)((char*)d_ws +
        ((2 * (size_t)B * sizeof(int) + 15) & ~(size_t)15));

    hipMemsetAsync(d_ws, 0, 2 * (size_t)B * sizeof(int), stream);
    fused_kernel<<<B * BPB, TPB, 0, stream>>>(logits, dbox4, cand, cnt, done, out);
}